// Round 8
// baseline (305.026 us; speedup 1.0000x reference)
//
#include <hip/hip_runtime.h>
#include <hip/hip_bf16.h>

typedef short bf16x8 __attribute__((ext_vector_type(8)));
typedef short bf16x4 __attribute__((ext_vector_type(4)));
typedef float f32x4 __attribute__((ext_vector_type(4)));

#define NG   9
#define CIN  1152
#define IG1  128
#define OG1  512
#define IG2  512
#define OG2  128
#define KP   576      // padded K per g2 (9 runs * 64)
#define HROW 5184     // NG * KP
#define MTOT 16384
#define OSTRIDE 1156  // epilogue LDS stride (floats)

__device__ __forceinline__ short f2bf(float f) {
    unsigned u = __float_as_uint(f);
    u += 0x7fff + ((u >> 16) & 1);   // RNE
    return (short)(u >> 16);
}
__device__ __forceinline__ short cvt1(float f) {
    __hip_bfloat16 h = __float2bfloat16(f);
    return *reinterpret_cast<short*>(&h);
}

// ---- prep (merged): w1 -> bf16 copy; w2 -> permuted+padded bf16 W2p.
// Slot mapping (NEW, alignment-friendly): slot r in run (g2,g1) holds o with o&63 == r:
//   olo = ceil((512*g2 - g1)/9); o = olo + ((r - (olo & 63)) & 63); valid iff j = 9o+g1-512g2 < 512.
// Bijective within the 64-slot run; k1g stores at slot = o & 63 (quad-aligned since o-quads are %4).
__global__ __launch_bounds__(256) void prep(const float* __restrict__ w1, const float* __restrict__ w2,
                                            short* __restrict__ w1b, short* __restrict__ w2p) {
    int i = blockIdx.x * 256 + threadIdx.x;
    const int NW1 = NG * OG1 * IG1;            // 589824
    if (i < NW1) { w1b[i] = f2bf(w1[i]); return; }
    int j = i - NW1;
    if (j >= NG * OG2 * KP) return;            // 663552
    int g2  = j / (OG2 * KP);
    int rem = j - g2 * (OG2 * KP);
    int o2  = rem / KP;
    int kp  = rem - o2 * KP;
    int g1 = kp >> 6, r = kp & 63;
    int olo = (512 * g2 - g1 + 8) / 9;         // ceil((512g2-g1)/9), numerator >= 0
    int o = olo + ((r - (olo & 63)) & 63);
    int jj = 9 * o + g1 - 512 * g2;            // >= 0 by construction
    float v = (jj < 512) ? w2[(g2 * OG2 + o2) * IG2 + jj] : 0.0f;
    w2p[j] = f2bf(v);
}

// ---- k1g: zero-LDS zero-barrier streaming GEMM1 + hardswish -> hbuf.
// 512 thr = 8 waves; block = (m-tile 32) x (o 512) for one g1. Wave w: o-slice [w*64,+64).
// Swapped MFMA (A = w1b o-rows, B = x m-rows) -> lane holds 4 consecutive o (aligned short4 stores).
// grid = NG * (MTOT/32) = 4608; bid = g1*512 + mt (consecutive blocks share g1's 128KB w1b in L2).
__global__ __launch_bounds__(512) void k1g(const float* __restrict__ x, const short* __restrict__ w1b,
                                           const float* __restrict__ b1, short* __restrict__ hbuf) {
    const int t = threadIdx.x;
    const int g1 = blockIdx.x >> 9;
    const int m0 = (blockIdx.x & 511) * 32;
    const int w = t >> 6, lane = t & 63, lr = lane & 15, lg = lane >> 4;
    const int o0 = w * 64;

    // x fragments direct (fp32 -> bf16 in regs); slice is L1/L2-hot across the 8 waves
    bf16x8 bx[2][4];
#pragma unroll
    for (int mi = 0; mi < 2; ++mi)
#pragma unroll
        for (int kf = 0; kf < 4; ++kf) {
            const float* p = x + (size_t)(m0 + mi * 16 + lr) * CIN + g1 * IG1 + kf * 32 + lg * 8;
            float4 v0 = *(const float4*)p;
            float4 v1 = *(const float4*)(p + 4);
            bf16x8 s;
            s[0]=cvt1(v0.x); s[1]=cvt1(v0.y); s[2]=cvt1(v0.z); s[3]=cvt1(v0.w);
            s[4]=cvt1(v1.x); s[5]=cvt1(v1.y); s[6]=cvt1(v1.z); s[7]=cvt1(v1.w);
            bx[mi][kf] = s;
        }

    f32x4 acc[4][2];
#pragma unroll
    for (int oi = 0; oi < 4; ++oi)
#pragma unroll
        for (int mi = 0; mi < 2; ++mi) acc[oi][mi] = (f32x4){0.f,0.f,0.f,0.f};

#pragma unroll
    for (int kf = 0; kf < 4; ++kf)
#pragma unroll
        for (int oi = 0; oi < 4; ++oi) {
            bf16x8 af = *(const bf16x8*)(w1b + ((size_t)(g1 * OG1 + o0 + oi * 16 + lr) * IG1 + kf * 32 + lg * 8));
#pragma unroll
            for (int mi = 0; mi < 2; ++mi)
                acc[oi][mi] = __builtin_amdgcn_mfma_f32_16x16x32_bf16(af, bx[mi][kf], acc[oi][mi], 0, 0, 0);
        }

    // epilogue: bias + hardswish -> hbuf[m][g2*576 + g1*64 + (o&63)]
#pragma unroll
    for (int oi = 0; oi < 4; ++oi) {
        int ob = o0 + oi * 16 + lg * 4;                 // 4 consecutive o per lane
        float4 bias = *(const float4*)(b1 + g1 * OG1 + ob);
        int g2f = (9 * ob + g1) >> 9;
        int g2l = (9 * (ob + 3) + g1) >> 9;
        int hcf = g2f * KP + (g1 << 6) + (ob & 63);     // quad base slot (ob%4==0 -> aligned)
#pragma unroll
        for (int mi = 0; mi < 2; ++mi) {
            size_t mrow = (size_t)(m0 + mi * 16 + lr) * HROW;
            bf16x4 sq;
#pragma unroll
            for (int q = 0; q < 4; ++q) {
                float v = acc[oi][mi][q] + ((const float*)&bias)[q];
                v = v * fminf(fmaxf(v + 3.0f, 0.0f), 6.0f) * (1.0f / 6.0f);
                sq[q] = cvt1(v);
            }
            if (g2f == g2l) {
                *(bf16x4*)(hbuf + mrow + hcf) = sq;     // 8B aligned store
            } else {                                    // rare: quad crosses a run boundary
#pragma unroll
                for (int q = 0; q < 4; ++q) {
                    int o = ob + q;
                    int g2q = (9 * o + g1) >> 9;
                    hbuf[mrow + g2q * KP + (g1 << 6) + (o & 63)] = sq[q];
                }
            }
        }
    }
}

// ---- k2g: per m-tile 32: 9 waves (wave = g2), K=576 dense vs W2p, direct-reg loads,
// no main-loop barriers; output via 2x 16-row LDS staging halves (74KB -> 2 blocks/CU).
__global__ __launch_bounds__(576) void k2g(const short* __restrict__ hbuf, const short* __restrict__ w2p,
                                           const float* __restrict__ b2, float* __restrict__ out) {
    __shared__ __attribute__((aligned(16))) float outs[16 * OSTRIDE];   // 73984 B
    const int t = threadIdx.x;
    const int m0 = blockIdx.x * 32;
    const int g2 = t >> 6;                 // wave id = output group
    const int lane = t & 63;
    const int lr = lane & 15, lg = lane >> 4;

    f32x4 acc[2][8];
#pragma unroll
    for (int mi = 0; mi < 2; ++mi)
#pragma unroll
        for (int nc = 0; nc < 8; ++nc) acc[mi][nc] = (f32x4){0.f, 0.f, 0.f, 0.f};

    const short* Ab = hbuf + (size_t)(m0 + lr) * HROW + g2 * KP + lg * 8;
    const short* Bb = w2p + (size_t)(g2 * OG2 + lr) * KP + lg * 8;

    for (int ks = 0; ks < 3; ++ks) {       // K = 576 in 3 chunks of 192 (6 k-frags)
        bf16x8 af[2][6];
#pragma unroll
        for (int mi = 0; mi < 2; ++mi)
#pragma unroll
            for (int kf = 0; kf < 6; ++kf)
                af[mi][kf] = *(const bf16x8*)(Ab + mi * 16 * HROW + (ks * 6 + kf) * 32);
#pragma unroll
        for (int kf = 0; kf < 6; ++kf) {
            bf16x8 bv[8];
#pragma unroll
            for (int nc = 0; nc < 8; ++nc)
                bv[nc] = *(const bf16x8*)(Bb + nc * 16 * KP + (ks * 6 + kf) * 32);
#pragma unroll
            for (int nc = 0; nc < 8; ++nc)
#pragma unroll
                for (int mi = 0; mi < 2; ++mi)
                    acc[mi][nc] = __builtin_amdgcn_mfma_f32_16x16x32_bf16(af[mi][kf], bv[nc], acc[mi][nc], 0, 0, 0);
        }
    }

    // epilogue: two 16-row halves (h == mi), stride-9 deposit (2-way bank alias = free),
    // then fully-coalesced float4 row writes
#pragma unroll
    for (int h = 0; h < 2; ++h) {
        __syncthreads();
#pragma unroll
        for (int nc = 0; nc < 8; ++nc) {
            int o2 = nc * 16 + lr;
            float bias = b2[g2 * OG2 + o2];
            int c = o2 * 9 + g2;
#pragma unroll
            for (int q = 0; q < 4; ++q)
                outs[(lg * 4 + q) * OSTRIDE + c] = acc[h][nc][q] + bias;
        }
        __syncthreads();
#pragma unroll
        for (int i = 0; i < 8; ++i) {
            int f4 = i * 576 + t;          // 16 rows x 288 float4 = 4608
            int row = f4 / 288, c4 = f4 - row * 288;
            float4 v = *(const float4*)&outs[row * OSTRIDE + c4 * 4];
            *(float4*)&out[(size_t)(m0 + h * 16 + row) * CIN + c4 * 4] = v;
        }
    }
}

extern "C" void kernel_launch(void* const* d_in, const int* in_sizes, int n_in,
                              void* d_out, int out_size, void* d_ws, size_t ws_size,
                              hipStream_t stream) {
    const float* x  = (const float*)d_in[0];
    const float* w1 = (const float*)d_in[1];
    const float* b1 = (const float*)d_in[2];
    const float* w2 = (const float*)d_in[3];
    const float* b2 = (const float*)d_in[4];
    float* out = (float*)d_out;

    short* hbuf = (short*)d_ws;                                                  // 169,869,312 B
    short* w1b  = (short*)((char*)d_ws + (size_t)MTOT * HROW * 2);               // 1,179,648 B
    short* w2p  = (short*)((char*)d_ws + (size_t)MTOT * HROW * 2 + (size_t)NG * OG1 * IG1 * 2); // 1,327,104 B

    const int nprep = NG * OG1 * IG1 + NG * OG2 * KP;                            // 1,253,376
    prep<<<(nprep + 255) / 256, 256, 0, stream>>>(w1, w2, w1b, w2p);
    k1g<<<NG * (MTOT / 32), 512, 0, stream>>>(x, w1b, b1, hbuf);
    k2g<<<MTOT / 32, 576, 0, stream>>>(hbuf, w2p, b2, out);
}

// Round 9
// 269.955 us; speedup vs baseline: 1.1299x; 1.1299x over previous
//
#include <hip/hip_runtime.h>

typedef short bf16x8 __attribute__((ext_vector_type(8)));
typedef short bf16x4 __attribute__((ext_vector_type(4)));
typedef float f32x4 __attribute__((ext_vector_type(4)));

#define NG   9
#define CIN  1152
#define OG1  512
#define OG2  128
#define IG2  512
#define KP   576      // w2p row length: 9 chunks of 64
#define MTOT 16384
#define MH   8192     // M half
#define OSTRIDE 1156  // k2 epilogue LDS stride (floats)

__device__ __forceinline__ short f2bf(float f) {
    unsigned u = __float_as_uint(f);
    u += 0x7fff + ((u >> 16) & 1);   // RNE
    return (short)(u >> 16);
}

// XOR-swizzle: permute low-3 bits of 16B-granule index by row&7 (self-inverse)
__device__ __forceinline__ int swz(int g, int row) {
    return (g & ~7) | ((g ^ (row & 7)) & 7);
}

// async global->LDS, 16B per lane; LDS base must be wave-uniform (HW adds lane*16)
__device__ __forceinline__ void gld16(const void* g, void* l) {
    __builtin_amdgcn_global_load_lds((const __attribute__((address_space(1))) unsigned int*)g,
                                     (__attribute__((address_space(3))) unsigned int*)l, 16, 0, 0);
}

// ---- prep: xb = bf16(x) (row-major); w1b = bf16(w1); w2p = permuted+padded bf16 w2.
// w2p[g2][o2][g1*64 + r] pairs with hidden col (a+r) of matrix g1, a = olo(g2,g1)&~7:
//   value = w2[g2][o2][9*(a+r)+g1-512*g2] if that index is in [0,512), else 0.
__global__ __launch_bounds__(256) void prep(const float* __restrict__ x, const float* __restrict__ w1,
                                            const float* __restrict__ w2, short* __restrict__ xb,
                                            short* __restrict__ w1b, short* __restrict__ w2p) {
    int i = blockIdx.x * 256 + threadIdx.x;
    const int NXB = MTOT * CIN / 8;            // 2359296 vec8 units
    if (i < NXB) {
        const float* p = x + (size_t)i * 8;
        float4 a = *(const float4*)p, b = *(const float4*)(p + 4);
        bf16x8 s;
        s[0]=f2bf(a.x); s[1]=f2bf(a.y); s[2]=f2bf(a.z); s[3]=f2bf(a.w);
        s[4]=f2bf(b.x); s[5]=f2bf(b.y); s[6]=f2bf(b.z); s[7]=f2bf(b.w);
        *(bf16x8*)(xb + (size_t)i * 8) = s;
        return;
    }
    int j = i - NXB;
    const int NW1 = NG * OG1 * 128;            // 589824
    if (j < NW1) { w1b[j] = f2bf(w1[j]); return; }
    j -= NW1;
    if (j >= NG * OG2 * KP) return;            // 663552
    int g2  = j / (OG2 * KP);
    int rem = j - g2 * (OG2 * KP);
    int o2  = rem / KP;
    int kp  = rem - o2 * KP;
    int g1 = kp >> 6, r = kp & 63;
    int olo = (512 * g2 - g1 + 8) / 9;         // first o of run (g2,g1); numerator >= 0
    int a   = olo & ~7;                        // 8-aligned window base; run fits [a,a+64)
    int jj  = 9 * (a + r) + g1 - 512 * g2;
    float v = (jj >= 0 && jj < 512) ? w2[(g2 * OG2 + o2) * IG2 + jj] : 0.0f;
    w2p[j] = f2bf(v);
}

// ---- k1: m97-style staged GEMM. Block = (g1, m-tile 128, o-tile 128), 256 thr (2x2 waves).
// K=128 single-shot: As/Bs staged once via global_load_lds (swizzled source), frags via
// ds_read_b128 (conflict-free), 64 MFMA/wave, direct bf16x4 row-run stores to hb[g1][m][o].
__global__ __launch_bounds__(256) void k1(const short* __restrict__ xb, const short* __restrict__ w1b,
                                          const float* __restrict__ b1, short* __restrict__ hb, int m_org) {
    __shared__ __attribute__((aligned(16))) char smem[65536];
    char* As = smem;             // [128 rows][16 granules][16B] x (m rows), swizzled
    char* Bs = smem + 32768;     // w1 (o rows), swizzled
    const int t = threadIdx.x;
    const int g1 = blockIdx.x >> 8;
    const int mt = (blockIdx.x >> 2) & 63;
    const int nt = blockIdx.x & 3;
    const int m0 = mt * 128, o0 = nt * 128;

#pragma unroll
    for (int i = 0; i < 8; ++i) {
        int u = i * 256 + t, row = u >> 4, g = u & 15, sg = swz(g, row);
        gld16(xb + (size_t)(m_org + m0 + row) * CIN + g1 * 128 + sg * 8,
              As + (i * 256 + (t & ~63)) * 16);
    }
#pragma unroll
    for (int i = 0; i < 8; ++i) {
        int u = i * 256 + t, row = u >> 4, g = u & 15, sg = swz(g, row);
        gld16(w1b + (size_t)(g1 * OG1 + o0 + row) * 128 + sg * 8,
              Bs + (i * 256 + (t & ~63)) * 16);
    }
    __syncthreads();   // drains vmcnt(0): staging complete

    const int lane = t & 63, w = t >> 6, lr = lane & 15, lg = lane >> 4;
    const int wr = w >> 1, wc = w & 1;        // wave tile 64m x 64o
    f32x4 acc[4][4];
#pragma unroll
    for (int mi = 0; mi < 4; ++mi)
#pragma unroll
        for (int ni = 0; ni < 4; ++ni) acc[mi][ni] = (f32x4){0.f,0.f,0.f,0.f};

#pragma unroll
    for (int kk = 0; kk < 4; ++kk) {
        int gi = kk * 4 + lg;
        bf16x8 as_[4], bs_[4];
#pragma unroll
        for (int mi = 0; mi < 4; ++mi) {
            int row = wr * 64 + mi * 16 + lr;
            as_[mi] = *(const bf16x8*)(As + (row * 16 + swz(gi, row)) * 16);
        }
#pragma unroll
        for (int ni = 0; ni < 4; ++ni) {
            int row = wc * 64 + ni * 16 + lr;
            bs_[ni] = *(const bf16x8*)(Bs + (row * 16 + swz(gi, row)) * 16);
        }
#pragma unroll
        for (int ni = 0; ni < 4; ++ni)
#pragma unroll
            for (int mi = 0; mi < 4; ++mi)   // swapped operands: D[o-quad][m]
                acc[mi][ni] = __builtin_amdgcn_mfma_f32_16x16x32_bf16(bs_[ni], as_[mi], acc[mi][ni], 0, 0, 0);
    }

    // epilogue: bias + hardswish -> hb[g1][m][o], lane holds 4 consecutive o (8B stores)
#pragma unroll
    for (int ni = 0; ni < 4; ++ni) {
        int oq = o0 + wc * 64 + ni * 16 + lg * 4;
        float4 bias = *(const float4*)(b1 + g1 * OG1 + oq);
#pragma unroll
        for (int mi = 0; mi < 4; ++mi) {
            int m = m0 + wr * 64 + mi * 16 + lr;
            bf16x4 sq;
#pragma unroll
            for (int q = 0; q < 4; ++q) {
                float v = acc[mi][ni][q] + ((const float*)&bias)[q];
                v = v * fminf(fmaxf(v + 3.0f, 0.0f), 6.0f) * (1.0f / 6.0f);
                sq[q] = f2bf(v);
            }
            *(bf16x4*)(hb + ((size_t)g1 * MH + m) * 512 + oq) = sq;
        }
    }
}

// ---- k2: block = m-tile 16, 576 thr = 9 waves (wave w = g2). K-loop over g1 chunks:
// As[16][512] staged per chunk via global_load_lds (dbuf, T3-min schedule); each wave reads
// its 64-col window [a(w,g1), +64) via swizzled ds_read; w2p B-frags direct from L2.
// Epilogue: r8-proven OSTRIDE LDS staging -> fully-coalesced float4 row writes.
__global__ __launch_bounds__(576) void k2(const short* __restrict__ hb, const short* __restrict__ w2p,
                                          const float* __restrict__ b2, float* __restrict__ out, int m_org) {
    __shared__ __attribute__((aligned(16))) char smem[73984];
    float* outs = (float*)smem;             // epilogue overlay [16][1156] fp32
    const int t = threadIdx.x;
    const int m0 = blockIdx.x * 16;
    const int w = t >> 6, lane = t & 63, lr = lane & 15, lg = lane >> 4;   // w = g2

    f32x4 acc[8];
#pragma unroll
    for (int nc = 0; nc < 8; ++nc) acc[nc] = (f32x4){0.f,0.f,0.f,0.f};

    // stage chunk: 16 KB = [16 rows][64 granules][16B], swizzled source
#define STAGE(g1v, buf) do {                                                         \
        _Pragma("unroll")                                                            \
        for (int i_ = 0; i_ < 2; ++i_) {                                             \
            int u_ = i_ * 576 + t;                                                   \
            if (u_ < 1024) {                                                         \
                int row_ = u_ >> 6, g_ = u_ & 63, sg_ = swz(g_, row_);               \
                gld16(hb + ((size_t)(g1v) * MH + m0 + row_) * 512 + sg_ * 8,         \
                      smem + (buf) * 16384 + (i_ * 576 + (t & ~63)) * 16);           \
            }                                                                        \
        } } while (0)

    STAGE(0, 0);
    __syncthreads();

    for (int g1 = 0; g1 < NG; ++g1) {
        if (g1 < 8) STAGE(g1 + 1, (g1 + 1) & 1);        // prefetch next chunk (other buffer)
        const char* Ab = smem + (g1 & 1) * 16384;
        int olo = (512 * w - g1 + 8) / 9;
        int a8  = (olo & ~7) >> 3;                      // granule base of this wave's window
#pragma unroll
        for (int kf = 0; kf < 2; ++kf) {
            int gi = (a8 + kf * 4 + lg) & 63;           // &63: overrun slots pair with w2p zeros
            bf16x8 af = *(const bf16x8*)(Ab + (lr * 64 + swz(gi, lr)) * 16);
#pragma unroll
            for (int nc = 0; nc < 8; ++nc) {
                bf16x8 bv = *(const bf16x8*)(w2p + (size_t)(w * OG2 + nc * 16 + lr) * KP + g1 * 64 + kf * 32 + lg * 8);
                acc[nc] = __builtin_amdgcn_mfma_f32_16x16x32_bf16(af, bv, acc[nc], 0, 0, 0);
            }
        }
        __syncthreads();                                // T3-min: one drain+barrier per chunk
    }

    // epilogue: deposit stride-9 cols into LDS, then coalesced full rows
#pragma unroll
    for (int nc = 0; nc < 8; ++nc) {
        int o2 = nc * 16 + lr;
        float bias = b2[w * OG2 + o2];
        int c = o2 * 9 + w;
#pragma unroll
        for (int q = 0; q < 4; ++q)
            outs[(lg * 4 + q) * OSTRIDE + c] = acc[nc][q] + bias;
    }
    __syncthreads();
#pragma unroll
    for (int i = 0; i < 8; ++i) {
        int f4 = i * 576 + t;                           // 16 rows x 288 float4 = 4608
        int row = f4 / 288, c4 = f4 - row * 288;
        float4 v = *(const float4*)&outs[row * OSTRIDE + c4 * 4];
        *(float4*)&out[(size_t)(m_org + m0 + row) * CIN + c4 * 4] = v;
    }
#undef STAGE
}

extern "C" void kernel_launch(void* const* d_in, const int* in_sizes, int n_in,
                              void* d_out, int out_size, void* d_ws, size_t ws_size,
                              hipStream_t stream) {
    const float* x  = (const float*)d_in[0];
    const float* w1 = (const float*)d_in[1];
    const float* b1 = (const float*)d_in[2];
    const float* w2 = (const float*)d_in[3];
    const float* b2 = (const float*)d_in[4];
    float* out = (float*)d_out;

    short* xb  = (short*)d_ws;                                           // 37,748,736 B
    short* w1b = (short*)((char*)d_ws + 37748736);                       //  1,179,648 B
    short* w2p = (short*)((char*)d_ws + 37748736 + 1179648);             //  1,327,104 B
    short* hb  = (short*)((char*)d_ws + 37748736 + 1179648 + 1327104);   // 75,497,472 B (half-M)
    // total ~115.8 MB, well under the 172.4 MB proven available in rounds 0-8

    prep<<<14112, 256, 0, stream>>>(x, w1, w2, xb, w1b, w2p);
    for (int h = 0; h < 2; ++h) {
        k1<<<NG * (MH / 128) * 4, 256, 0, stream>>>(xb, w1b, b1, hb, h * MH);   // 2304 blocks
        k2<<<MH / 16, 576, 0, stream>>>(hb, w2p, b2, out, h * MH);              // 512 blocks
    }
}

// Round 10
// 220.835 us; speedup vs baseline: 1.3812x; 1.2224x over previous
//
#include <hip/hip_runtime.h>

typedef short bf16x8 __attribute__((ext_vector_type(8)));
typedef short bf16x4 __attribute__((ext_vector_type(4)));
typedef float f32x4 __attribute__((ext_vector_type(4)));

#define NG   9
#define CIN  1152
#define OG1  512
#define OG2  128
#define IG2  512
#define KP   576      // w2p row length: 9 chunks of 64
#define MTOT 16384

__device__ __forceinline__ short f2bf(float f) {
    unsigned u = __float_as_uint(f);
    u += 0x7fff + ((u >> 16) & 1);   // RNE
    return (short)(u >> 16);
}
// swizzles: permute low-3 bits of granule index by row&7 (self-inverse)
__device__ __forceinline__ int swz16(int g, int row) { return (g & ~7) | ((g ^ (row & 7)) & 7); }
__device__ __forceinline__ int swz8 (int g, int row) { return g ^ (row & 7); }

__device__ __forceinline__ void gld16(const void* g, void* l) {
    __builtin_amdgcn_global_load_lds((const __attribute__((address_space(1))) unsigned int*)g,
                                     (__attribute__((address_space(3))) unsigned int*)l, 16, 0, 0);
}

// ---- prep: w1b = bf16(w1); w2p[g2][o2][g1*64+r] = bf16(w2[g2][o2][9*(a+r)+g1-512*g2]) or 0,
// a = min(olo & ~7, 448), olo = ceil((512*g2-g1)/9). Window [a,a+64) covers the whole run.
__global__ __launch_bounds__(256) void prep(const float* __restrict__ w1, const float* __restrict__ w2,
                                            short* __restrict__ w1b, short* __restrict__ w2p) {
    int i = blockIdx.x * 256 + threadIdx.x;
    const int NW1 = NG * OG1 * 128;            // 589824
    if (i < NW1) { w1b[i] = f2bf(w1[i]); return; }
    int j = i - NW1;
    if (j >= NG * OG2 * KP) return;            // 663552
    int g2  = j / (OG2 * KP);
    int rem = j - g2 * (OG2 * KP);
    int o2  = rem / KP;
    int kp  = rem - o2 * KP;
    int g1 = kp >> 6, r = kp & 63;
    int olo = (512 * g2 - g1 + 8) / 9;
    int a   = olo & ~7;  if (a > 448) a = 448;
    int jj  = 9 * (a + r) + g1 - 512 * g2;
    float v = (jj >= 0 && jj < 512) ? w2[(g2 * OG2 + o2) * IG2 + jj] : 0.0f;
    w2p[j] = f2bf(v);
}

// ---- k1: per (g1, m-tile 128, o-tile 128) GEMM, K=128 single-shot. 512 thr = 2m x 4n waves.
// A (x) staged via regs (fp32->bf16->swizzled ds_write); B (w1b) via global_load_lds.
// Swapped MFMA -> lane holds 4 consecutive o -> aligned bf16x4 stores to hb[g1][m][o].
__global__ __launch_bounds__(512) void k1(const float* __restrict__ x, const short* __restrict__ w1b,
                                          const float* __restrict__ b1, short* __restrict__ hb) {
    __shared__ __attribute__((aligned(16))) char smem[65536];
    char* As = smem;             // [128 m-rows][16 granules][16B], swizzled
    char* Bs = smem + 32768;     // [128 o-rows][16 granules][16B], swizzled
    const int t = threadIdx.x;
    const int g1 = blockIdx.x >> 9;
    const int mt = (blockIdx.x >> 2) & 127;
    const int nt = blockIdx.x & 3;
    const int m0 = mt * 128, o0 = nt * 128;

    // stage B first (async, no deps)
#pragma unroll
    for (int i = 0; i < 4; ++i) {
        int u = i * 512 + t, row = u >> 4, g = u & 15;
        gld16(w1b + (size_t)(g1 * OG1 + o0 + row) * 128 + swz16(g, row) * 8,
              Bs + (i * 512 + (t & ~63)) * 16);
    }
    // stage A through registers with inline fp32->bf16
#pragma unroll
    for (int i = 0; i < 4; ++i) {
        int u = i * 512 + t, row = u >> 4, g = u & 15;
        const float* p = x + (size_t)(m0 + row) * CIN + g1 * 128 + g * 8;
        float4 v0 = *(const float4*)p, v1 = *(const float4*)(p + 4);
        bf16x8 s;
        s[0]=f2bf(v0.x); s[1]=f2bf(v0.y); s[2]=f2bf(v0.z); s[3]=f2bf(v0.w);
        s[4]=f2bf(v1.x); s[5]=f2bf(v1.y); s[6]=f2bf(v1.z); s[7]=f2bf(v1.w);
        *(bf16x8*)(As + ((size_t)(row * 16 + swz16(g, row))) * 16) = s;
    }
    __syncthreads();

    const int lane = t & 63, w = t >> 6, lr = lane & 15, lg = lane >> 4;
    const int wr = w >> 2, wc = w & 3;        // wave tile: 64 m x 32 o
    f32x4 acc[4][2];
#pragma unroll
    for (int mi = 0; mi < 4; ++mi)
#pragma unroll
        for (int ni = 0; ni < 2; ++ni) acc[mi][ni] = (f32x4){0.f,0.f,0.f,0.f};

#pragma unroll
    for (int kk = 0; kk < 4; ++kk) {
        int gi = kk * 4 + lg;
        bf16x8 as_[4], bs_[2];
#pragma unroll
        for (int mi = 0; mi < 4; ++mi) {
            int row = wr * 64 + mi * 16 + lr;
            as_[mi] = *(const bf16x8*)(As + (row * 16 + swz16(gi, row)) * 16);
        }
#pragma unroll
        for (int ni = 0; ni < 2; ++ni) {
            int row = wc * 32 + ni * 16 + lr;
            bs_[ni] = *(const bf16x8*)(Bs + (row * 16 + swz16(gi, row)) * 16);
        }
#pragma unroll
        for (int ni = 0; ni < 2; ++ni)
#pragma unroll
            for (int mi = 0; mi < 4; ++mi)   // swapped: D[o][m]
                acc[mi][ni] = __builtin_amdgcn_mfma_f32_16x16x32_bf16(bs_[ni], as_[mi], acc[mi][ni], 0, 0, 0);
    }

    // epilogue: bias + hardswish -> hb[g1][m][o]
#pragma unroll
    for (int ni = 0; ni < 2; ++ni) {
        int oq = o0 + wc * 32 + ni * 16 + lg * 4;
        float4 bias = *(const float4*)(b1 + g1 * OG1 + oq);
#pragma unroll
        for (int mi = 0; mi < 4; ++mi) {
            int m = m0 + wr * 64 + mi * 16 + lr;
            bf16x4 sq;
#pragma unroll
            for (int q = 0; q < 4; ++q) {
                float v = acc[mi][ni][q] + ((const float*)&bias)[q];
                v = v * fminf(fmaxf(v + 3.0f, 0.0f), 6.0f) * (1.0f / 6.0f);
                sq[q] = f2bf(v);
            }
            *(bf16x4*)(hb + ((size_t)g1 * MTOT + m) * 512 + oq) = sq;
        }
    }
}

// ---- k2: per-g2 GEMM, tile M=128 x N=128, K=576 as 9 steps of 64 (g1-windows of hb).
// m97 structure: dbuf LDS (64KB), gld16 staging (swizzled source), ds_read_b128 frags.
// Direct stride-9 fp32 output; XCD-colocating swizzle so the 9 g2-blocks of one m-tile
// share one XCD's L2 and their partial output lines merge before eviction.
__global__ __launch_bounds__(512) void k2(const short* __restrict__ hb, const short* __restrict__ w2p,
                                          const float* __restrict__ b2, float* __restrict__ out) {
    __shared__ __attribute__((aligned(16))) char smem[65536];   // [2 buf][A 16KB | B 16KB]
    const int t = threadIdx.x;
    // decode with XCD-colocate swizzle: p = xcd + 8*(mtg*9 + g2)
    int p = blockIdx.x;                 // 1152 = 8 * 144
    int xcd = p & 7, slot = p >> 3;     // slot < 144
    int g2 = slot % 9, mtg = slot / 9;  // mtg < 16
    int m0 = (xcd + 8 * mtg) * 128;
    const int lane = t & 63, w = t >> 6, lr = lane & 15, lg = lane >> 4;
    const int wr = w >> 2, wc = w & 3;  // wave tile: 64 m x 32 o2

#define STAGE(g1v, buf) do {                                                          \
        int olo_ = (512 * g2 - (g1v) + 8) / 9;                                        \
        int a_   = olo_ & ~7; if (a_ > 448) a_ = 448;                                 \
        _Pragma("unroll")                                                             \
        for (int i_ = 0; i_ < 2; ++i_) {                                              \
            int u_ = i_ * 512 + t, row_ = u_ >> 3, sub_ = u_ & 7;                     \
            gld16(hb + ((size_t)(g1v) * MTOT + m0 + row_) * 512 + a_ + swz8(sub_, row_) * 8, \
                  smem + (buf) * 32768 + (i_ * 512 + (t & ~63)) * 16);                \
        }                                                                             \
        _Pragma("unroll")                                                             \
        for (int i_ = 0; i_ < 2; ++i_) {                                              \
            int u_ = i_ * 512 + t, row_ = u_ >> 3, sub_ = u_ & 7;                     \
            gld16(w2p + ((size_t)g2 * OG2 + row_) * KP + (g1v) * 64 + swz8(sub_, row_) * 8, \
                  smem + (buf) * 32768 + 16384 + (i_ * 512 + (t & ~63)) * 16);        \
        } } while (0)

    f32x4 acc[4][2];
#pragma unroll
    for (int mi = 0; mi < 4; ++mi)
#pragma unroll
        for (int ni = 0; ni < 2; ++ni) acc[mi][ni] = (f32x4){0.f,0.f,0.f,0.f};

    STAGE(0, 0);
    __syncthreads();

    for (int g1 = 0; g1 < NG; ++g1) {
        if (g1 < 8) STAGE(g1 + 1, (g1 + 1) & 1);
        const char* Ab = smem + (g1 & 1) * 32768;
        const char* Bb = Ab + 16384;
#pragma unroll
        for (int kf = 0; kf < 2; ++kf) {
            int gi = kf * 4 + lg;
            bf16x8 ah[4], bw[2];
#pragma unroll
            for (int mi = 0; mi < 4; ++mi) {
                int row = wr * 64 + mi * 16 + lr;
                ah[mi] = *(const bf16x8*)(Ab + (row * 8 + swz8(gi, row)) * 16);
            }
#pragma unroll
            for (int ni = 0; ni < 2; ++ni) {
                int row = wc * 32 + ni * 16 + lr;
                bw[ni] = *(const bf16x8*)(Bb + (row * 8 + swz8(gi, row)) * 16);
            }
#pragma unroll
            for (int ni = 0; ni < 2; ++ni)
#pragma unroll
                for (int mi = 0; mi < 4; ++mi)   // swapped: D[o2][m]
                    acc[mi][ni] = __builtin_amdgcn_mfma_f32_16x16x32_bf16(bw[ni], ah[mi], acc[mi][ni], 0, 0, 0);
        }
        __syncthreads();
    }
#undef STAGE

    // epilogue: bias + direct interleaved stores out[m][o2*9+g2]
#pragma unroll
    for (int ni = 0; ni < 2; ++ni) {
        int o2q = wc * 32 + ni * 16 + lg * 4;
        float4 bias = *(const float4*)(b2 + g2 * OG2 + o2q);
#pragma unroll
        for (int mi = 0; mi < 4; ++mi) {
            int m = m0 + wr * 64 + mi * 16 + lr;
            float* orow = out + (size_t)m * CIN;
#pragma unroll
            for (int q = 0; q < 4; ++q)
                orow[(o2q + q) * 9 + g2] = acc[mi][ni][q] + ((const float*)&bias)[q];
        }
    }
}

extern "C" void kernel_launch(void* const* d_in, const int* in_sizes, int n_in,
                              void* d_out, int out_size, void* d_ws, size_t ws_size,
                              hipStream_t stream) {
    const float* x  = (const float*)d_in[0];
    const float* w1 = (const float*)d_in[1];
    const float* b1 = (const float*)d_in[2];
    const float* w2 = (const float*)d_in[3];
    const float* b2 = (const float*)d_in[4];
    float* out = (float*)d_out;

    short* w1b = (short*)d_ws;                                   //   1,179,648 B
    short* w2p = (short*)((char*)d_ws + 1179648);                //   1,327,104 B
    short* hb  = (short*)((char*)d_ws + 1179648 + 1327104);      // 150,994,944 B  (total 153.5 MB, < r0-proven 172.4 MB)

    const int nprep = NG * OG1 * 128 + NG * OG2 * KP;            // 1,253,376
    prep<<<(nprep + 255) / 256, 256, 0, stream>>>(w1, w2, w1b, w2p);
    k1<<<NG * 128 * 4, 512, 0, stream>>>(x, w1b, b1, hb);        // 4608 blocks
    k2<<<1152, 512, 0, stream>>>(hb, w2p, b2, out);              // 1152 blocks
}